// Round 6
// baseline (310.230 us; speedup 1.0000x reference)
//
#include <hip/hip_runtime.h>

#define EPS 1e-12f
typedef __attribute__((ext_vector_type(8))) short short8;   // 8 x bf16
typedef __attribute__((ext_vector_type(4))) float f32x4;    // MFMA acc

#define MFMA(a, b, c) __builtin_amdgcn_mfma_f32_16x16x32_bf16(a, b, c, 0, 0, 0)

// ---- bf16 hi/lo split helpers (RNE hi, RNE lo) ----------------------------
__device__ __forceinline__ unsigned rne16(unsigned u) {
  return u + 0x7FFFu + ((u >> 16) & 1u);
}
__device__ __forceinline__ void split2(float f, unsigned short& h,
                                       unsigned short& l) {
  unsigned u = __float_as_uint(f);
  unsigned rh = rne16(u);
  float hf = __uint_as_float(rh & 0xFFFF0000u);
  unsigned rl = rne16(__float_as_uint(f - hf));
  h = (unsigned short)(rh >> 16);
  l = (unsigned short)(rl >> 16);
}
__device__ __forceinline__ void split_pair(float f0, float f1,
                                           unsigned& hp, unsigned& lp) {
  unsigned u0 = __float_as_uint(f0), u1 = __float_as_uint(f1);
  unsigned r0 = rne16(u0), r1 = rne16(u1);
  float h0 = __uint_as_float(r0 & 0xFFFF0000u);
  float h1 = __uint_as_float(r1 & 0xFFFF0000u);
  hp = (r0 >> 16) | (r1 & 0xFFFF0000u);
  unsigned v0 = rne16(__float_as_uint(f0 - h0));
  unsigned v1 = rne16(__float_as_uint(f1 - h1));
  lp = (v0 >> 16) | (v1 & 0xFFFF0000u);
}
__device__ __forceinline__ void split8(float4 a, float4 b, short8& h, short8& l) {
  union { unsigned u[4]; short8 s; } H, L;
  split_pair(a.x, a.y, H.u[0], L.u[0]);
  split_pair(a.z, a.w, H.u[1], L.u[1]);
  split_pair(b.x, b.y, H.u[2], L.u[2]);
  split_pair(b.z, b.w, H.u[3], L.u[3]);
  h = H.s; l = L.s;
}

// ---------------------------------------------------------------------------
// Prep: w [512 d][64 k] fp32 -> wT hi/lo bf16 [64 k][512 d]
// ---------------------------------------------------------------------------
extern "C" __global__ __launch_bounds__(256) void netvlad_prep(
    const float* __restrict__ w, unsigned short* __restrict__ wTh,
    unsigned short* __restrict__ wTl)
{
  int tg = blockIdx.x * 256 + threadIdx.x;   // = k*512 + d
  int k = tg >> 9, d = tg & 511;
  unsigned short h, l;
  split2(w[d * 64 + k], h, l);
  wTh[tg] = h;
  wTl[tg] = l;
}

// ---------------------------------------------------------------------------
// Kernel A: s = x@w (MFMA bf16-split), barrier-free K-loop with explicit
// 2-stage REGISTER double buffer for x and wT (defeats the compiler's
// load-serialize-at-32-VGPR schedule seen in R5). Softmax in registers;
// aT hi/lo bf16 [b][64 k][1024 n] + asum. Grid 1024, 4 waves/block.
// ---------------------------------------------------------------------------
extern "C" __global__ __launch_bounds__(256, 4) void netvlad_assign(
    const float* __restrict__ x, const unsigned short* __restrict__ wTh,
    const unsigned short* __restrict__ wTl, unsigned short* __restrict__ aTh,
    unsigned short* __restrict__ aTl, float* __restrict__ asum)
{
  __shared__ unsigned short ath[64 * 72];  // aT tile [k][px], pad 72
  __shared__ unsigned short atl[64 * 72];
  __shared__ float asp[4 * 64];

  const int t = threadIdx.x;
  const int lane = t & 63, wv = t >> 6;
  const int lo4 = lane & 15, hi4 = lane >> 4;
  const int b = blockIdx.x >> 4;
  const int nblk = (blockIdx.x & 15) << 6;   // 64-px block within batch

  f32x4 acc[4] = {};

  // lane's A-row: px = blk*64 + wv*16 + lo4 ; d-chunk = hi4*8
  const float* xp =
      x + ((size_t)(blockIdx.x << 6) + (wv << 4) + lo4) * 512 + (hi4 << 3);
  const unsigned short* wph = wTh + (lo4 << 9) + (hi4 << 3);
  const unsigned short* wpl = wTl + (lo4 << 9) + (hi4 << 3);

  float4 xc0[2], xc1[2];
  short8 wh[2][4], wl[2][4];

  // preload stage 0
  xc0[0] = *(const float4*)xp;
  xc1[0] = *(const float4*)(xp + 4);
#pragma unroll
  for (int nt = 0; nt < 4; ++nt) {
    wh[0][nt] = *(const short8*)(wph + nt * 8192);
    wl[0][nt] = *(const short8*)(wpl + nt * 8192);
  }

#pragma unroll
  for (int it = 0; it < 16; ++it) {
    const int cur = it & 1, nxt = cur ^ 1;
    const int dn = ((it + 1) & 15) << 5;   // next d0 (wraps; harmless L1 hit)
    // issue ALL next-stage loads before touching current stage
    xc0[nxt] = *(const float4*)(xp + dn);
    xc1[nxt] = *(const float4*)(xp + dn + 4);
#pragma unroll
    for (int nt = 0; nt < 4; ++nt) {
      wh[nxt][nt] = *(const short8*)(wph + nt * 8192 + dn);
      wl[nxt][nt] = *(const short8*)(wpl + nt * 8192 + dn);
    }
    short8 xh, xl;
    split8(xc0[cur], xc1[cur], xh, xl);
#pragma unroll
    for (int nt = 0; nt < 4; ++nt) {
      acc[nt] = MFMA(xh, wh[cur][nt], acc[nt]);
      acc[nt] = MFMA(xl, wh[cur][nt], acc[nt]);
      acc[nt] = MFMA(xh, wl[cur][nt], acc[nt]);
    }
  }

  // softmax over k (4 nt regs x 16 lo4 lanes); px = wv*16 + hi4*4 + r
  float asum_p[4] = {0.f, 0.f, 0.f, 0.f};
#pragma unroll
  for (int r = 0; r < 4; ++r) {
    float s0 = acc[0][r], s1 = acc[1][r], s2 = acc[2][r], s3 = acc[3][r];
    float m = fmaxf(fmaxf(s0, s1), fmaxf(s2, s3));
    m = fmaxf(m, __shfl_xor(m, 1));
    m = fmaxf(m, __shfl_xor(m, 2));
    m = fmaxf(m, __shfl_xor(m, 4));
    m = fmaxf(m, __shfl_xor(m, 8));
    float e0 = __expf(s0 - m), e1 = __expf(s1 - m);
    float e2 = __expf(s2 - m), e3 = __expf(s3 - m);
    float s = e0 + e1 + e2 + e3;
    s += __shfl_xor(s, 1);
    s += __shfl_xor(s, 2);
    s += __shfl_xor(s, 4);
    s += __shfl_xor(s, 8);
    float inv = 1.0f / s;
    e0 *= inv; e1 *= inv; e2 *= inv; e3 *= inv;
    asum_p[0] += e0; asum_p[1] += e1; asum_p[2] += e2; asum_p[3] += e3;
    acc[0][r] = e0; acc[1][r] = e1; acc[2][r] = e2; acc[3][r] = e3;
  }
  // scatter hi/lo into LDS transpose tile
#pragma unroll
  for (int nt = 0; nt < 4; ++nt)
#pragma unroll
    for (int r = 0; r < 4; ++r) {
      unsigned short h, l;
      split2(acc[nt][r], h, l);
      int idx = ((nt << 4) + lo4) * 72 + (wv << 4) + (hi4 << 2) + r;
      ath[idx] = h;
      atl[idx] = l;
    }
  // asum partials
#pragma unroll
  for (int nt = 0; nt < 4; ++nt) {
    float v = asum_p[nt];
    v += __shfl_xor(v, 16);
    v += __shfl_xor(v, 32);
    if (lane < 16) asp[(wv << 6) + (nt << 4) + lane] = v;
  }
  __syncthreads();
  if (t < 64) {
    float s = asp[t] + asp[64 + t] + asp[128 + t] + asp[192 + t];
    atomicAdd(&asum[(b << 6) + t], s);
  }
  // cooperative coalesced store: 64 k x 64 px
  {
    const int k = t >> 2, px0 = (t & 3) << 4;
    const size_t go = ((size_t)((b << 6) + k) << 10) + nblk + px0;
    *(short8*)(aTh + go)     = *(short8*)&ath[k * 72 + px0];
    *(short8*)(aTh + go + 8) = *(short8*)&ath[k * 72 + px0 + 8];
    *(short8*)(aTl + go)     = *(short8*)&atl[k * 72 + px0];
    *(short8*)(aTl + go + 8) = *(short8*)&atl[k * 72 + px0 + 8];
  }
}

// ---------------------------------------------------------------------------
// Kernel B: vkd[b][d][k] = sum_n aT[k][n]*x[n][d] (MFMA bf16-split).
// Grid 1024 = 64 b x 16 d-slices(32). 4 waves; wave = 16 k x 32 d.
// x pre-split+transposed into LDS u16 (pad 74 -> odd dword stride, b128
// reads ~conflict-free), single barrier/iter dbuf. aT + x-rows prefetched
// into 2-stage register buffers.
// ---------------------------------------------------------------------------
extern "C" __global__ __launch_bounds__(256, 4) void netvlad_vlad(
    const float* __restrict__ x, const unsigned short* __restrict__ aTh,
    const unsigned short* __restrict__ aTl, float* __restrict__ vkd)
{
  __shared__ unsigned short xth[2][32 * 74];   // xT [d][n] u16
  __shared__ unsigned short xtl[2][32 * 74];
  const int t = threadIdx.x;
  const int lane = t & 63, wv = t >> 6;
  const int lo4 = lane & 15, hi4 = lane >> 4;
  const int b = blockIdx.x >> 4;
  const int ds = (blockIdx.x & 15) << 5;    // 32-d slice
  const int np2 = (t & 31) << 1;            // staging n-pair
  const int dc = (t >> 5) << 2;             // staging d-chunk (4)
  const float* xsb = x + ((size_t)(b << 10)) * 512 + ds + dc;
  const unsigned short* aph =
      aTh + ((size_t)((b << 6) + (wv << 4) + lo4) << 10) + (hi4 << 3);
  const unsigned short* apl =
      aTl + ((size_t)((b << 6) + (wv << 4) + lo4) << 10) + (hi4 << 3);

  f32x4 acc[2] = {};
  float4 xr0, xr1;
  short8 ah[2][2], al[2][2];   // [stage][nf]

  xr0 = *(const float4*)(xsb + (size_t)np2 * 512);
  xr1 = *(const float4*)(xsb + (size_t)(np2 + 1) * 512);
#pragma unroll
  for (int nf = 0; nf < 2; ++nf) {
    ah[0][nf] = *(const short8*)(aph + (nf << 5));
    al[0][nf] = *(const short8*)(apl + (nf << 5));
  }

#pragma unroll
  for (int it = 0; it < 16; ++it) {
    const int cur = it & 1, nxt = cur ^ 1;
    const int n0 = it << 6;
    unsigned short* th = xth[cur];
    unsigned short* tl = xtl[cur];
    // stage current x regs (pre-split, transposed, ushort2-packed)
    {
      float f0[4] = {xr0.x, xr0.y, xr0.z, xr0.w};
      float f1[4] = {xr1.x, xr1.y, xr1.z, xr1.w};
#pragma unroll
      for (int j = 0; j < 4; ++j) {
        unsigned short h0, l0, h1, l1;
        split2(f0[j], h0, l0);
        split2(f1[j], h1, l1);
        ushort2 hp; hp.x = h0; hp.y = h1;
        ushort2 lp; lp.x = l0; lp.y = l1;
        *(ushort2*)&th[(dc + j) * 74 + np2] = hp;
        *(ushort2*)&tl[(dc + j) * 74 + np2] = lp;
      }
    }
    __syncthreads();
    // prefetch next stage (x rows + aT) before consuming current
    if (it < 15) {
      xr0 = *(const float4*)(xsb + (size_t)(n0 + 64 + np2) * 512);
      xr1 = *(const float4*)(xsb + (size_t)(n0 + 64 + np2 + 1) * 512);
    }
    {
      const int nn = ((it + 1) & 15) << 6;
#pragma unroll
      for (int nf = 0; nf < 2; ++nf) {
        ah[nxt][nf] = *(const short8*)(aph + nn + (nf << 5));
        al[nxt][nf] = *(const short8*)(apl + nn + (nf << 5));
      }
    }
#pragma unroll
    for (int nf = 0; nf < 2; ++nf)
#pragma unroll
      for (int dt = 0; dt < 2; ++dt) {
        const int xo = ((dt << 4) + lo4) * 74 + (nf << 5) + (hi4 << 3);
        short8 bh = *(short8*)&th[xo];
        short8 bl = *(short8*)&tl[xo];
        acc[dt] = MFMA(ah[cur][nf], bh, acc[dt]);
        acc[dt] = MFMA(ah[cur][nf], bl, acc[dt]);
        acc[dt] = MFMA(al[cur][nf], bh, acc[dt]);
      }
  }
  // D: row k = wv*16 + hi4*4 + r, col d = ds + dt*16 + lo4
#pragma unroll
  for (int dt = 0; dt < 2; ++dt) {
    float* vb = vkd + (((size_t)(b << 9) + ds + (dt << 4) + lo4) << 6)
              + (wv << 4) + (hi4 << 2);
    *(float4*)vb = make_float4(acc[dt][0], acc[dt][1], acc[dt][2], acc[dt][3]);
  }
}

// ---------------------------------------------------------------------------
// Kernel C1: v = vkd + asum[k]*C[d][k]; write out[b][d][k]; r_k partials.
// ---------------------------------------------------------------------------
extern "C" __global__ __launch_bounds__(256) void netvlad_fin1(
    const float* __restrict__ vkd, const float* __restrict__ Cm,
    const float* __restrict__ asum, float* __restrict__ out,
    float* __restrict__ r_buf)
{
  __shared__ float rp[16 * 64];
  const int t = threadIdx.x;
  const int b = blockIdx.x >> 4;
  const int ds = (blockIdx.x & 15) << 5;
  const int k4 = (t & 15) << 2;
  const int dg = t >> 4;                 // 0..15
  float4 asv = *(const float4*)(asum + (b << 6) + k4);
  float4 racc = {0.f, 0.f, 0.f, 0.f};
#pragma unroll
  for (int j = 0; j < 2; ++j) {
    int d = ds + dg * 2 + j;
    size_t off = (((size_t)(b << 9) + d) << 6) + k4;
    float4 v = *(const float4*)(vkd + off);
    float4 c = *(const float4*)(Cm + ((size_t)d << 6) + k4);
    v.x += asv.x * c.x; v.y += asv.y * c.y;
    v.z += asv.z * c.z; v.w += asv.w * c.w;
    *(float4*)(out + off) = v;
    racc.x = fmaf(v.x, v.x, racc.x); racc.y = fmaf(v.y, v.y, racc.y);
    racc.z = fmaf(v.z, v.z, racc.z); racc.w = fmaf(v.w, v.w, racc.w);
  }
  *(float4*)&rp[dg * 64 + k4] = racc;
  __syncthreads();
  if (t < 64) {
    float r = 0.f;
#pragma unroll
    for (int g = 0; g < 16; ++g) r += rp[g * 64 + t];
    atomicAdd(&r_buf[(b << 6) + t], r);
  }
}

// ---------------------------------------------------------------------------
// Kernel C3: per-batch scales from r_buf (redundant per block) + apply.
// ---------------------------------------------------------------------------
extern "C" __global__ __launch_bounds__(256) void netvlad_fin3(
    float* __restrict__ out, const float* __restrict__ r_buf)
{
  __shared__ float sc[64];
  const int t = threadIdx.x;
  const int b = blockIdx.x >> 3;
  if (t < 64) {
    float r = r_buf[(b << 6) + t];
    float g = r / (r + EPS);
    g += __shfl_xor(g, 1);
    g += __shfl_xor(g, 2);
    g += __shfl_xor(g, 4);
    g += __shfl_xor(g, 8);
    g += __shfl_xor(g, 16);
    g += __shfl_xor(g, 32);
    sc[t] = 1.0f / (sqrtf(r + EPS) * sqrtf(g + EPS));
  }
  __syncthreads();
  float4* o4 = (float4*)out;
#pragma unroll
  for (int c = 0; c < 4; ++c) {
    int idx = blockIdx.x * 1024 + c * 256 + t;
    float4 v = o4[idx];
    int k4 = (idx & 15) * 4;
    v.x *= sc[k4]; v.y *= sc[k4 + 1]; v.z *= sc[k4 + 2]; v.w *= sc[k4 + 3];
    o4[idx] = v;
  }
}

// ---------------------------------------------------------------------------
extern "C" void kernel_launch(void* const* d_in, const int* in_sizes, int n_in,
                              void* d_out, int out_size, void* d_ws,
                              size_t ws_size, hipStream_t stream)
{
  const float* x  = (const float*)d_in[0];  // [64,32,32,512]
  const float* w  = (const float*)d_in[1];  // [512,64]
  const float* Cm = (const float*)d_in[2];  // [512,64]
  float* out = (float*)d_out;               // [64, 512*64]

  // workspace carve: ~25.3 MB total
  unsigned short* aTh = (unsigned short*)d_ws;            // 4,194,304 u16
  unsigned short* aTl = aTh + 4194304;                    // 4,194,304 u16
  float* vkd = (float*)(aTl + 4194304);                   // 2,097,152 f32
  unsigned short* wTh = (unsigned short*)(vkd + 2097152); // 32768 u16
  unsigned short* wTl = wTh + 32768;                      // 32768 u16
  float* asum = (float*)(wTl + 32768);                    // 4096 f32
  float* r_buf = asum + 4096;                             // 4096 f32

  hipMemsetAsync(asum, 0, 2 * 4096 * sizeof(float), stream);  // asum + r_buf

  netvlad_prep  <<< 128, 256, 0, stream>>>(w, wTh, wTl);
  netvlad_assign<<<1024, 256, 0, stream>>>(x, wTh, wTl, aTh, aTl, asum);
  netvlad_vlad  <<<1024, 256, 0, stream>>>(x, aTh, aTl, vkd);
  netvlad_fin1  <<<1024, 256, 0, stream>>>(vkd, Cm, asum, out, r_buf);
  netvlad_fin3  <<< 512, 256, 0, stream>>>(out, r_buf);
}